// Round 1
// baseline (712.316 us; speedup 1.0000x reference)
//
#include <hip/hip_runtime.h>

#define C 128
#define HH 128
#define WW 128
#define BB 4

// ---------------------------------------------------------------------------
// Layouts (all fp32):
//   x,y,out : [B][C][H][W]
//   xt      : [B][W][H][C]  (phase-1 scan input, per-(b,w) slab of [H][C])
//   yt1     : [B][W][H][C]  (phase-1 gate)
//   yt2     : [B][H][W][C]  (phase-2 gate, per-(b,h) slab of [W][C])
//   hs_t/hn_t: [B][H][W][C] (phase-1 output == phase-2 input slabs)
//   outA    : [B][H][W][C] = hse+hsw   (reuses xt)
//   outB    : [B][H][W][C] = hne+hnw   (reuses yt1)
// ---------------------------------------------------------------------------

// xt[b][w][h][c] = x[b][c][h][w]   (per-(b,h) 128x128 transpose)
__global__ __launch_bounds__(256) void k_transpose_x(const float* __restrict__ x,
                                                     float* __restrict__ xt) {
  __shared__ float tile[128][129];
  const int b = blockIdx.x >> 7;
  const int h = blockIdx.x & 127;
  const int t = threadIdx.x;
  const int half = t >> 7;
  const int lane = t & 127;
  const float* src = x + (size_t)b * 2097152 + (size_t)h * 128;  // [c][w] @ c*16384 + w
  for (int c0 = 0; c0 < 128; c0 += 2) {
    const int c = c0 + half;
    tile[c][lane] = src[(size_t)c * 16384 + lane];
  }
  __syncthreads();
  float* dst = xt + (size_t)b * 2097152 + (size_t)h * 128;  // [w][c] @ w*16384 + c
  for (int w0 = 0; w0 < 128; w0 += 2) {
    const int w = w0 + half;
    dst[(size_t)w * 16384 + lane] = tile[lane][w];
  }
}

// yt1[b][w][h][c] = y[b][c][h][w];  yt2[b][h][w][c] = y[b][c][h][w]
__global__ __launch_bounds__(256) void k_transpose_y(const float* __restrict__ y,
                                                     float* __restrict__ yt1,
                                                     float* __restrict__ yt2) {
  __shared__ float tile[128][129];
  const int b = blockIdx.x >> 7;
  const int h = blockIdx.x & 127;
  const int t = threadIdx.x;
  const int half = t >> 7;
  const int lane = t & 127;
  const float* src = y + (size_t)b * 2097152 + (size_t)h * 128;
  for (int c0 = 0; c0 < 128; c0 += 2) {
    const int c = c0 + half;
    tile[c][lane] = src[(size_t)c * 16384 + lane];
  }
  __syncthreads();
  float* d1 = yt1 + (size_t)b * 2097152 + (size_t)h * 128;          // [w][c] @ w*16384 + c
  float* d2 = yt2 + ((size_t)(b * 128 + h)) * 16384;                // [w][c] @ w*128 + c
  for (int w0 = 0; w0 < 128; w0 += 2) {
    const int w = w0 + half;
    const float v = tile[lane][w];
    d1[(size_t)w * 16384 + lane] = v;
    d2[(size_t)w * 128 + lane] = v;
  }
}

// ---------------------------------------------------------------------------
// One directional gated scan for a single column line.
// Block = 256 threads: group A (t<128) computes the feedforward conv (Wa),
// group B (t>=128) computes the recurrent conv (Wb) + combine + state update.
// ACC: 0 = store h to global; 1 = store h into LDS accum; 2 = store h+accum.
// in/gate slabs: [128 steps][128 ch], step stride = 128 floats.
// out element for step s: out_base + p(s)*out_stride + ch.
// ---------------------------------------------------------------------------
template <bool RELU_FIRST, bool REVERSE, int ACC>
__device__ __forceinline__ void scan_col(
    const float* __restrict__ in_slab, const float* __restrict__ gate_slab,
    float* __restrict__ out_base, int out_stride,
    const float* __restrict__ Wa, const float* __restrict__ Ba,
    const float* __restrict__ Wb, const float* __restrict__ Bb,
    float* xbuf, float* hbuf, float* rabuf, float* accum) {
  const int t = threadIdx.x;
  const bool isA = (t < 128);
  const int ch = t & 127;

  // Own weight row -> 128 VGPRs (fully static indexing).
  float4 wr[32];
  {
    const float* Wrow = (isA ? Wa : Wb) + (size_t)ch * C;
#pragma unroll
    for (int i = 0; i < 32; ++i) wr[i] = ((const float4*)Wrow)[i];
  }

  auto pidx = [](int s) -> int { return REVERSE ? (127 - s) : s; };

  float ba_c = 0.f, bb_c = 0.f, gcur = 0.f;
  if (isA) {
    xbuf[0 * C + ch] = in_slab[(size_t)pidx(0) * C + ch];
    xbuf[1 * C + ch] = in_slab[(size_t)pidx(1) * C + ch];
  } else {
    ba_c = Ba[ch];
    bb_c = Bb[ch];
    gcur = gate_slab[(size_t)pidx(0) * C + ch];  // gate used at step 1
  }
  __syncthreads();

  // step 0: h0 = (relu?)(in[0]); no convs, no gate.
  if (!isA) {
    float h = xbuf[0 * C + ch];
    if (RELU_FIRST) h = fmaxf(h, 0.f);
    hbuf[0 * C + ch] = h;
    if (ACC == 0)
      out_base[(size_t)pidx(0) * out_stride + ch] = h;
    else if (ACC == 1)
      accum[(size_t)pidx(0) * C + ch] = h;
    else
      out_base[(size_t)pidx(0) * out_stride + ch] = h + accum[(size_t)pidx(0) * C + ch];
  }
  __syncthreads();

#pragma unroll 1
  for (int s = 1; s < 128; ++s) {
    const int slot = s & 1;
    // prefetch next-step global data (consumed after the mid barrier)
    float xnext = 0.f, gnext = 0.f;
    if (isA) {
      if (s < 127) xnext = in_slab[(size_t)pidx(s + 1) * C + ch];
    } else {
      if (s < 127) gnext = gate_slab[(size_t)pidx(s) * C + ch];  // gate for step s+1
    }
    // 128-long dot product: A uses staged x, B uses previous h. Broadcast LDS reads.
    const float* src = isA ? (xbuf + slot * C) : (hbuf + (slot ^ 1) * C);
    float4 a4 = make_float4(0.f, 0.f, 0.f, 0.f);
#pragma unroll
    for (int i = 0; i < 32; ++i) {
      const float4 v = ((const float4*)src)[i];
      a4.x = fmaf(wr[i].x, v.x, a4.x);
      a4.y = fmaf(wr[i].y, v.y, a4.y);
      a4.z = fmaf(wr[i].z, v.z, a4.z);
      a4.w = fmaf(wr[i].w, v.w, a4.w);
    }
    const float acc = (a4.x + a4.y) + (a4.z + a4.w);
    if (isA) rabuf[slot * C + ch] = acc;
    __syncthreads();  // mid: ra[s] visible to B
    if (!isA) {
      const float rav = rabuf[slot * C + ch];
      float h = rav + ba_c + (acc + bb_c) * gcur;
      h = fmaxf(h, 0.f);
      hbuf[slot * C + ch] = h;
      if (ACC == 0)
        out_base[(size_t)pidx(s) * out_stride + ch] = h;
      else if (ACC == 1)
        accum[(size_t)pidx(s) * C + ch] = h;
      else
        out_base[(size_t)pidx(s) * out_stride + ch] = h + accum[(size_t)pidx(s) * C + ch];
      gcur = gnext;
    } else {
      if (s < 127) xbuf[(slot ^ 1) * C + ch] = xnext;
    }
    __syncthreads();  // end of step
  }
}

// Phase 1: south (hs) + north (hn) scans over H. 1024 blocks: [scan(2)][b(4)][w(128)]
__global__ __launch_bounds__(256, 2) void k_scan_phase1(
    const float* __restrict__ xt, const float* __restrict__ yt1,
    float* __restrict__ hs_t, float* __restrict__ hn_t,
    const float* w1, const float* b1, const float* w2, const float* b2,
    const float* w9, const float* b9, const float* w10, const float* b10) {
  __shared__ __align__(16) float xbuf[2 * C];
  __shared__ __align__(16) float hbuf[2 * C];
  __shared__ __align__(16) float rabuf[2 * C];
  const int id = blockIdx.x;
  const int scan = id >> 9;
  const int col = id & 511;  // b*128 + w
  const int b = col >> 7, w = col & 127;
  const float* in_slab = xt + (size_t)col * 16384;
  const float* gate = yt1 + (size_t)col * 16384;
  if (scan == 0) {
    float* outb = hs_t + (size_t)b * 2097152 + (size_t)w * C;  // [k][..] stride 16384
    scan_col<false, false, 0>(in_slab, gate, outb, 16384, w1, b1, w2, b2, xbuf, hbuf, rabuf, nullptr);
  } else {
    float* outb = hn_t + (size_t)b * 2097152 + (size_t)w * C;
    scan_col<true, true, 0>(in_slab, gate, outb, 16384, w9, b9, w10, b10, xbuf, hbuf, rabuf, nullptr);
  }
}

// Phase 2: SE+SW (from hs_t -> outA) and NE+NW (from hn_t -> outB).
// 1024 blocks: [grp(2)][b(4)][h(128)]. Pair accumulated through 64KB LDS.
__global__ __launch_bounds__(256, 2) void k_scan_phase2(
    const float* __restrict__ hs_t, const float* __restrict__ hn_t,
    const float* __restrict__ yt2, float* __restrict__ outA, float* __restrict__ outB,
    const float* w4, const float* b4, const float* w5, const float* b5,
    const float* w7, const float* b7, const float* w8, const float* b8,
    const float* w12, const float* b12, const float* w13, const float* b13,
    const float* w15, const float* b15, const float* w16, const float* b16) {
  __shared__ __align__(16) float xbuf[2 * C];
  __shared__ __align__(16) float hbuf[2 * C];
  __shared__ __align__(16) float rabuf[2 * C];
  __shared__ __align__(16) float accum[128 * C];  // 64 KB
  const int id = blockIdx.x;
  const int grp = id >> 9;
  const int col = id & 511;  // b*128 + h
  const size_t base = (size_t)col * 16384;
  const float* in_slab = (grp == 0 ? hs_t : hn_t) + base;
  const float* gate = yt2 + base;
  float* outp = (grp == 0 ? outA : outB) + base;
  if (grp == 0) {
    scan_col<true, false, 1>(in_slab, gate, nullptr, 0, w4, b4, w5, b5, xbuf, hbuf, rabuf, accum);
    __syncthreads();
    scan_col<true, true, 2>(in_slab, gate, outp, C, w7, b7, w8, b8, xbuf, hbuf, rabuf, accum);
  } else {
    scan_col<true, false, 1>(in_slab, gate, nullptr, 0, w12, b12, w13, b13, xbuf, hbuf, rabuf, accum);
    __syncthreads();
    scan_col<true, true, 2>(in_slab, gate, outp, C, w15, b15, w16, b16, xbuf, hbuf, rabuf, accum);
  }
}

// out[b][c][h][w] = outA[b][h][w][c] + outB[b][h][w][c]
__global__ __launch_bounds__(256) void k_final(const float* __restrict__ outA,
                                               const float* __restrict__ outB,
                                               float* __restrict__ out) {
  __shared__ float tile[128][129];
  const int b = blockIdx.x >> 7;
  const int h = blockIdx.x & 127;
  const int t = threadIdx.x;
  const int half = t >> 7;
  const int lane = t & 127;
  const float* pa = outA + ((size_t)(b * 128 + h)) * 16384;  // [w][c]
  const float* pb = outB + ((size_t)(b * 128 + h)) * 16384;
  for (int w0 = 0; w0 < 128; w0 += 2) {
    const int w = w0 + half;
    tile[w][lane] = pa[(size_t)w * 128 + lane] + pb[(size_t)w * 128 + lane];
  }
  __syncthreads();
  float* dst = out + (size_t)b * 2097152 + (size_t)h * 128;  // [c][w] @ c*16384 + w
  for (int c0 = 0; c0 < 128; c0 += 2) {
    const int c = c0 + half;
    dst[(size_t)c * 16384 + lane] = tile[lane][c];
  }
}

extern "C" void kernel_launch(void* const* d_in, const int* in_sizes, int n_in,
                              void* d_out, int out_size, void* d_ws, size_t ws_size,
                              hipStream_t stream) {
  const float* x = (const float*)d_in[0];
  const float* y = (const float*)d_in[1];
  const float* w1 = (const float*)d_in[2];
  const float* b1 = (const float*)d_in[3];
  const float* w2 = (const float*)d_in[4];
  const float* b2 = (const float*)d_in[5];
  const float* w4 = (const float*)d_in[6];
  const float* b4 = (const float*)d_in[7];
  const float* w5 = (const float*)d_in[8];
  const float* b5 = (const float*)d_in[9];
  const float* w7 = (const float*)d_in[10];
  const float* b7 = (const float*)d_in[11];
  const float* w8 = (const float*)d_in[12];
  const float* b8 = (const float*)d_in[13];
  const float* w9 = (const float*)d_in[14];
  const float* b9 = (const float*)d_in[15];
  const float* w10 = (const float*)d_in[16];
  const float* b10 = (const float*)d_in[17];
  const float* w12 = (const float*)d_in[18];
  const float* b12 = (const float*)d_in[19];
  const float* w13 = (const float*)d_in[20];
  const float* b13 = (const float*)d_in[21];
  const float* w15 = (const float*)d_in[22];
  const float* b15 = (const float*)d_in[23];
  const float* w16 = (const float*)d_in[24];
  const float* b16 = (const float*)d_in[25];

  const size_t N1 = (size_t)BB * C * HH * WW;  // 8M floats = 32MB
  if (ws_size < 5 * N1 * sizeof(float)) return;  // need 160MB scratch

  float* ws = (float*)d_ws;
  float* xt = ws;
  float* yt1 = ws + N1;
  float* yt2 = ws + 2 * N1;
  float* hs_t = ws + 3 * N1;
  float* hn_t = ws + 4 * N1;
  float* outA = xt;   // free after phase 1
  float* outB = yt1;  // free after phase 1

  dim3 blk(256);
  k_transpose_x<<<512, blk, 0, stream>>>(x, xt);
  k_transpose_y<<<512, blk, 0, stream>>>(y, yt1, yt2);
  k_scan_phase1<<<1024, blk, 0, stream>>>(xt, yt1, hs_t, hn_t, w1, b1, w2, b2, w9, b9, w10, b10);
  k_scan_phase2<<<1024, blk, 0, stream>>>(hs_t, hn_t, yt2, outA, outB,
                                          w4, b4, w5, b5, w7, b7, w8, b8,
                                          w12, b12, w13, b13, w15, b15, w16, b16);
  k_final<<<512, blk, 0, stream>>>(outA, outB, (float*)d_out);
}